// Round 11
// baseline (741.525 us; speedup 1.0000x reference)
//
#include <hip/hip_runtime.h>
#include <hip/hip_bf16.h>
#include <hip/hip_fp16.h>

#define N_NODES 20000
#define E_EDGES 320000
#define CIN 128
#define HDIM 128
#define EDGE_DIM 16
#define SDIM 3
#define KS 3
#define KK 27           // 3^3 kernel weight matrices
#define NB 28           // 27 spline blocks + 1 root-weight block
#define KSTEPS 112      // NB*128/32 k-steps of the fused GEMM
#define TLD (KK * 128)  // node-major T leading dim = 3456 shorts (root not stored)
#define WLD 28          // per-edge fp32 spline-weight stride (floats, 7 x float4)
#define MLP_HID 6

typedef __attribute__((ext_vector_type(8))) short v8s;   // 8 bf16 (4 VGPRs)
typedef __attribute__((ext_vector_type(4))) float v4f;   // MFMA accumulator
typedef unsigned short ush;

static __device__ __forceinline__ short f2bf(float v) {
    unsigned u = __float_as_uint(v);
    unsigned r = (u + 0x7fffu + ((u >> 16) & 1u)) >> 16;   // RTNE
    return (short)r;
}
static __device__ __forceinline__ float bf2f_lo(unsigned u) {   // low short
    return __uint_as_float(u << 16);
}
static __device__ __forceinline__ float bf2f_hi(unsigned u) {   // high short
    return __uint_as_float(u & 0xffff0000u);
}
static __device__ __forceinline__ unsigned pack2bf(float a, float b) {
    return ((unsigned)(ush)f2bf(a)) | (((unsigned)(ush)f2bf(b)) << 16);
}

// ---------------------------------------------------------------------------
// edge_index dtype detect + decode (int64 vs int32 storage)
// ---------------------------------------------------------------------------
__global__ void detect_kernel(const unsigned int* __restrict__ e, int* __restrict__ flag) {
    __shared__ int s_nz;
    if (threadIdx.x == 0) s_nz = 0;
    __syncthreads();
    unsigned int v = e[threadIdx.x * 2 + 1];
    if (v != 0) atomicAdd(&s_nz, 1);
    __syncthreads();
    if (threadIdx.x == 0) *flag = (s_nz > 0) ? 1 : 0;
}

__global__ void decode_edges(const void* __restrict__ eraw, const int* __restrict__ flag,
                             int* __restrict__ e32, int n) {
    int i = blockIdx.x * blockDim.x + threadIdx.x;
    if (i >= n) return;
    if (*flag) e32[i] = ((const int*)eraw)[i];
    else       e32[i] = (int)(((const long long*)eraw)[i]);
}

// ---------------------------------------------------------------------------
// Edge MLP (16->6 relu ->3 sigmoid) -> (frac[3], lo[3]) per edge, packed 16 B.
// ---------------------------------------------------------------------------
__global__ void edge_basis(const float* __restrict__ ea,
                           const float* __restrict__ Wp1, const float* __restrict__ bp1,
                           const float* __restrict__ Wp2, const float* __restrict__ bp2,
                           float4* __restrict__ fb) {
    __shared__ float sW1[EDGE_DIM * MLP_HID];
    __shared__ float sb1[MLP_HID];
    __shared__ float sW2[MLP_HID * SDIM];
    __shared__ float sb2[SDIM];
    int t = threadIdx.x;
    if (t < EDGE_DIM * MLP_HID) sW1[t] = Wp1[t];
    if (t < MLP_HID)            sb1[t] = bp1[t];
    if (t < MLP_HID * SDIM)     sW2[t] = Wp2[t];
    if (t < SDIM)               sb2[t] = bp2[t];
    __syncthreads();
    int e = blockIdx.x * blockDim.x + t;
    if (e >= E_EDGES) return;

    float a[EDGE_DIM];
#pragma unroll
    for (int i = 0; i < EDGE_DIM; i++) a[i] = ea[(long)e * EDGE_DIM + i];

    float hid[MLP_HID];
#pragma unroll
    for (int j = 0; j < MLP_HID; j++) {
        float s = sb1[j];
#pragma unroll
        for (int i = 0; i < EDGE_DIM; i++) s += a[i] * sW1[i * MLP_HID + j];
        hid[j] = fmaxf(s, 0.f);
    }

    float fr[SDIM];
    unsigned lp = 0;
#pragma unroll
    for (int d = 0; d < SDIM; d++) {
        float s = sb2[d];
#pragma unroll
        for (int j = 0; j < MLP_HID; j++) s += hid[j] * sW2[j * SDIM + d];
        float u = 1.f / (1.f + expf(-s));
        float v = u * (float)(KS - 1);
        float l = floorf(v);
        l = fminf(fmaxf(l, 0.f), (float)(KS - 2));
        fr[d] = v - l;
        lp |= ((unsigned)(int)l) << (8 * d);
    }
    float4 o;
    o.x = fr[0]; o.y = fr[1]; o.z = fr[2]; o.w = __uint_as_float(lp);
    fb[e] = o;
}

// ---------------------------------------------------------------------------
// CSR build binned by dst — built once, reused for 3 layers.
// Hierarchical 3-dispatch scan.
// ---------------------------------------------------------------------------
__global__ void zero_int(int* __restrict__ p, int n) {
    int i = blockIdx.x * blockDim.x + threadIdx.x;
    if (i < n) p[i] = 0;
}

__global__ void hist_kernel(const int* __restrict__ dst, int* __restrict__ hist) {
    int e = blockIdx.x * blockDim.x + threadIdx.x;
    if (e >= E_EDGES) return;
    atomicAdd(&hist[dst[e]], 1);
}

__global__ void scan_blk(const int* __restrict__ hist, int* __restrict__ rowptr,
                         int* __restrict__ bsum, int B) {
    __shared__ int sh[256];
    int i = blockIdx.x * 256 + threadIdx.x;
    int v = (i < B) ? hist[i] : 0;
    sh[threadIdx.x] = v;
    __syncthreads();
    for (int off = 1; off < 256; off <<= 1) {
        int t = (threadIdx.x >= off) ? sh[threadIdx.x - off] : 0;
        __syncthreads();
        sh[threadIdx.x] += t;
        __syncthreads();
    }
    if (i < B) rowptr[i] = sh[threadIdx.x] - v;        // block-local exclusive
    if (threadIdx.x == 255) bsum[blockIdx.x] = sh[255];
}

__global__ void scan_top(int* __restrict__ bsum, int nb) {
    __shared__ int sh[256];
    int v = (threadIdx.x < nb) ? bsum[threadIdx.x] : 0;
    sh[threadIdx.x] = v;
    __syncthreads();
    for (int off = 1; off < 256; off <<= 1) {
        int t = (threadIdx.x >= off) ? sh[threadIdx.x - off] : 0;
        __syncthreads();
        sh[threadIdx.x] += t;
        __syncthreads();
    }
    if (threadIdx.x < nb) bsum[threadIdx.x] = sh[threadIdx.x] - v;   // exclusive
}

__global__ void scan_add(int* __restrict__ rowptr, const int* __restrict__ bsum, int B) {
    int i = blockIdx.x * 256 + threadIdx.x;
    if (i < B) rowptr[i] += bsum[blockIdx.x];
    if (i == 0) rowptr[B] = E_EDGES;
}

__global__ void perm_kernel(const int* __restrict__ dst,
                            const int* __restrict__ rowptr, int* __restrict__ cursor,
                            int* __restrict__ eperm) {
    int e = blockIdx.x * blockDim.x + threadIdx.x;
    if (e >= E_EDGES) return;
    int bin = dst[e];
    int pos = rowptr[bin] + atomicAdd(&cursor[bin], 1);
    eperm[pos] = e;
}

// ---------------------------------------------------------------------------
// Pack per-edge metadata into CSR order: src index + DENSE 27 fp32 spline
// weights (stride 28 floats = 7 float4).
// ---------------------------------------------------------------------------
__global__ void pack_w27(const int* __restrict__ eperm, const int* __restrict__ src,
                         const float4* __restrict__ fb,
                         int* __restrict__ srcp, float* __restrict__ w28p) {
    int j = blockIdx.x * blockDim.x + threadIdx.x;
    if (j >= E_EDGES) return;
    int e = eperm[j];
    srcp[j] = src[e];
    float4 f = fb[e];
    unsigned lp = __float_as_uint(f.w);
    float fr[3] = {f.x, f.y, f.z};
    float t[3][3];
#pragma unroll
    for (int d = 0; d < 3; d++) {
        int lo = (lp >> (8 * d)) & 255;
        float fd = fr[d];
#pragma unroll
        for (int q = 0; q < 3; q++)
            t[d][q] = (q == lo) ? (1.f - fd) : (q == lo + 1) ? fd : 0.f;
    }
    float out[WLD];
#pragma unroll
    for (int k2 = 0; k2 < 3; k2++)
#pragma unroll
        for (int k1 = 0; k1 < 3; k1++)
#pragma unroll
            for (int k0 = 0; k0 < 3; k0++)
                out[k2 * 9 + k1 * 3 + k0] = t[0][k0] * t[1][k1] * t[2][k2];
    out[27] = 0.f;
    float* op = w28p + (size_t)j * WLD;
#pragma unroll
    for (int q = 0; q < WLD / 4; q++) *(float4*)(op + 4 * q) = *(float4*)(out + 4 * q);
}

// ---------------------------------------------------------------------------
// Pack [W (27 blocks) | Wr] of ALL 3 LAYERS -> bf16 MFMA B-fragment layout.
// Layout [layer][flat_ks=kb*4+ks][nt][64][8] — one fused K=3584 B panel.
// ---------------------------------------------------------------------------
__global__ void packW3_kernel(const float* __restrict__ W0, const float* __restrict__ Wr0,
                              const float* __restrict__ W1, const float* __restrict__ Wr1,
                              const float* __restrict__ W2, const float* __restrict__ Wr2,
                              short* __restrict__ hi) {
    int gid = blockIdx.x * blockDim.x + threadIdx.x;
    if (gid >= 3 * NB * 4 * 8 * 64) return;
    int lane = gid & 63;
    int nt = (gid >> 6) & 7;
    int ks = (gid >> 9) & 3;
    int kb2 = gid >> 11;           // 0..83
    int layer = kb2 / NB;
    int kb = kb2 - layer * NB;
    const float* W  = (layer == 0) ? W0  : (layer == 1) ? W1  : W2;
    const float* Wr = (layer == 0) ? Wr0 : (layer == 1) ? Wr1 : Wr2;
    int i0 = ks * 32 + ((lane >> 4) & 3) * 8;
    int o = nt * 16 + (lane & 15);
    const float* src = (kb < KK) ? (W + (long)kb * 16384 + (long)i0 * 128 + o)
                                 : (Wr + (long)i0 * 128 + o);
    long off = ((long)(((size_t)layer * NB + kb) * 4 + ks) * 8 + nt) * 64 * 8
             + (long)lane * 8;
#pragma unroll
    for (int j = 0; j < 8; j++) {
        float v = src[(long)j * 128];
        hi[off + j] = f2bf(v);
    }
}

// ---------------------------------------------------------------------------
// x (fp32) -> xb (bf16 row-major) once; later layers' activations are written
// bf16 row-major by the GEMM epilogue directly.
// ---------------------------------------------------------------------------
__global__ void conv_xb(const float* __restrict__ x, ush* __restrict__ xb) {
    int i = blockIdx.x * blockDim.x + threadIdx.x;
    if (i >= N_NODES * CIN / 4) return;
    float4 v = ((const float4*)x)[i];
    uint2 d;
    d.x = pack2bf(v.x, v.y);
    d.y = pack2bf(v.z, v.w);
    ((uint2*)xb)[i] = d;
}

// ---------------------------------------------------------------------------
// accumT v7: 4 WAVES PER 256-THREAD BLOCK, ONE NODE PER WAVE. Metadata
// (rowptr, srcp, w28p) is wave-uniform -> still scalarized onto the SMEM
// pipe per wave. The R10 lesson: SMEM completes out-of-order, so prefetch
// depth can't hide its latency (lgkmcnt(0) drains everything) — therefore
// hide it with TLP instead: 4-wave blocks raise residency from ~10 waves/CU
// (64-thr workgroup limit) toward the register-budget cap, so one wave's
// lgkmcnt drain overlaps another's 108-cycle FMA burst.
// Per-wave code identical to v6 (depth-4 rotating slots, depth-8 srcp).
// T written node-major, full 256 B coalesced lines per (n,k).
// ---------------------------------------------------------------------------
__global__ __launch_bounds__(256) void accumT_kernel(
    const ush* __restrict__ act, const int* __restrict__ rowptr,
    const int* __restrict__ srcp, const float* __restrict__ w28p,
    ush* __restrict__ T, int n0, int nmax)
{
    int lane = threadIdx.x & 63;
    int wave = threadIdx.x >> 6;
    int n = n0 + blockIdx.x * 4 + wave;
    if (n >= nmax) return;
    int jb = rowptr[n], je = rowptr[n + 1];

    float acc[KK][2];
#pragma unroll
    for (int k = 0; k < KK; k++) { acc[k][0] = 0.f; acc[k][1] = 0.f; }

    const ush* actl = act + lane * 2;                 // channel-pair base
    const float4* w4 = (const float4*)w28p;           // stride 7 per edge

    if (jb < je) {
        int last = je - 1;
        unsigned xs[4];
        float4 ws[4][7];
        int sn[4];
        // fill slots with edges jb..jb+3 (clamped); preload srcs of jb+4..jb+7
#pragma unroll
        for (int q = 0; q < 4; q++) {
            int jq = (jb + q > last) ? last : jb + q;
            int s = srcp[jq];
            xs[q] = *(const unsigned*)(actl + (size_t)s * 128);
#pragma unroll
            for (int t = 0; t < 7; t++) ws[q][t] = w4[(size_t)jq * 7 + t];
            int jf = (jb + 4 + q > last) ? last : jb + 4 + q;
            sn[q] = srcp[jf];
        }

        for (int j = jb; j < je; j += 4) {
#pragma unroll
            for (int s = 0; s < 4; s++) {
                if (s == 0 || j + s < je) {           // wave-uniform guard
                    float x0 = bf2f_lo(xs[s]), x1 = bf2f_hi(xs[s]);
                    float w[28];
#pragma unroll
                    for (int t = 0; t < 7; t++) *(float4*)(w + 4 * t) = ws[s][t];
#pragma unroll
                    for (int k = 0; k < KK; k++) {
                        acc[k][0] += w[k] * x0;
                        acc[k][1] += w[k] * x1;
                    }
                }
                // refill slot s <- edge j+4+s (clamped; never computed if pad)
                int jn = (j + 4 + s > last) ? last : j + 4 + s;
                xs[s] = *(const unsigned*)(actl + (size_t)sn[s] * 128);
#pragma unroll
                for (int t = 0; t < 7; t++) ws[s][t] = w4[(size_t)jn * 7 + t];
                int jf = (j + 8 + s > last) ? last : j + 8 + s;
                sn[s] = srcp[jf];
            }
        }
    }

    ush* tp = T + (size_t)(n - n0) * TLD + lane * 2;
#pragma unroll
    for (int k = 0; k < KK; k++) {
        *(unsigned*)(tp + (size_t)k * 128) = pack2bf(acc[k][0], acc[k][1]);
    }
}

// ---------------------------------------------------------------------------
// gemm2 v8 (unchanged from R10): 1024 threads / 16 waves, ONE m-tile per
// block -> 625 fine-grained blocks. Wave owns 7 k-steps, fully unrolled.
// 16-way cross-wave reduce via LDS (69.6 KB) in 2 passes.
// ---------------------------------------------------------------------------
__global__ __launch_bounds__(1024) void gemm2_kernel(
    const ush* __restrict__ T, const ush* __restrict__ act,
    const short* __restrict__ Wh, const float* __restrict__ bias,
    ush* __restrict__ actout, float* __restrict__ fout,
    int n0, int relu)
{
    __shared__ float S[1024][17];
    int lane = threadIdx.x & 63;
    int wave = threadIdx.x >> 6;               // k-slice 0..15
    int mtr = blockIdx.x;

    v4f acc[8];
#pragma unroll
    for (int nt = 0; nt < 8; nt++) acc[nt] = (v4f){0.f, 0.f, 0.f, 0.f};

    int r15 = lane & 15;
    int sub = (lane >> 4) & 3;
    int arow = mtr * 16 + r15;                 // chunk-local row
    const ush* tp = T + (size_t)arow * TLD + sub * 8;
    const ush* ap = act + (size_t)(n0 + arow) * 128 + sub * 8;

    int ks0 = wave * (KSTEPS / 16);            // 7 k-steps per wave
#pragma unroll
    for (int i = 0; i < KSTEPS / 16; i++) {
        int ks = ks0 + i;
        v8s a = (ks < KK * 4) ? *(const v8s*)(tp + ks * 32)
                              : *(const v8s*)(ap + (ks - KK * 4) * 32);
        const short* wb = Wh + (size_t)ks * 4096 + (size_t)lane * 8;
#pragma unroll
        for (int nt = 0; nt < 8; nt++) {
            v8s b = *(const v8s*)(wb + (size_t)nt * 512);
            acc[nt] = __builtin_amdgcn_mfma_f32_16x16x32_bf16(a, b, acc[nt], 0, 0, 0);
        }
    }

    // 16-way cross-wave reduce + epilogue: 2 passes (2 column halves)
    int r  = threadIdx.x >> 6;                 // output row in m-tile (0..15)
    int cl = threadIdx.x & 63;                 // column within the 64-col half
    int row = n0 + mtr * 16 + r;
#pragma unroll
    for (int p = 0; p < 2; p++) {
        __syncthreads();
#pragma unroll
        for (int q = 0; q < 16; q++)
            S[threadIdx.x][q] = acc[p * 4 + (q >> 2)][q & 3];
        __syncthreads();
        int c = p * 64 + cl;                   // global output column
        int ln  = (cl & 15) + 16 * (r >> 2);   // source lane of C-frag
        int idx = (cl >> 4) * 4 + (r & 3);     // nt_local*4 + reg
        float s = 0.f;
#pragma unroll
        for (int w = 0; w < 16; w++) s += S[w * 64 + ln][idx];
        s += bias[c];
        if (relu) s = fmaxf(s, 0.f);
        if (actout) {
            actout[(size_t)row * 128 + c] = (ush)f2bf(s);
        } else {
            fout[(size_t)row * 128 + c] = s;
        }
    }
}

// ---------------------------------------------------------------------------
extern "C" void kernel_launch(void* const* d_in, const int* in_sizes, int n_in,
                              void* d_out, int out_size, void* d_ws, size_t ws_size,
                              hipStream_t stream) {
    const float* x   = (const float*)d_in[0];
    const void*  eix = d_in[1];
    const float* ea  = (const float*)d_in[2];
    const float* Wp1 = (const float*)d_in[3];
    const float* bp1 = (const float*)d_in[4];
    const float* Wp2 = (const float*)d_in[5];
    const float* bp2 = (const float*)d_in[6];
    const float* W[3]  = {(const float*)d_in[7],  (const float*)d_in[10], (const float*)d_in[13]};
    const float* Wr[3] = {(const float*)d_in[8],  (const float*)d_in[11], (const float*)d_in[14]};
    const float* b[3]  = {(const float*)d_in[9],  (const float*)d_in[12], (const float*)d_in[15]};
    float* out = (float*)d_out;

    char* ws = (char*)d_ws;
    size_t off = 0;
    auto walloc = [&](size_t bytes) -> void* {
        void* p = ws + off;
        off = (off + bytes + 255) & ~(size_t)255;
        return p;
    };
    int*    flag    = (int*)   walloc(sizeof(int));
    int*    e32     = (int*)   walloc(sizeof(int) * 2 * E_EDGES);
    float4* fb      = (float4*)walloc(sizeof(float4) * (size_t)E_EDGES);
    int*    srcp    = (int*)   walloc(sizeof(int) * E_EDGES);
    int*    eperm   = (int*)   walloc(sizeof(int) * E_EDGES);
    float*  w28p    = (float*) walloc(sizeof(float) * (size_t)E_EDGES * WLD);
    int*    histcur = (int*)   walloc(sizeof(int) * (size_t)N_NODES * 2);
    int*    rowptr  = (int*)   walloc(sizeof(int) * (N_NODES + 1));
    int*    bsum    = (int*)   walloc(sizeof(int) * 256);
    ush*    xb      = (ush*)   walloc(sizeof(ush) * (size_t)N_NODES * 128);
    ush*    a1      = (ush*)   walloc(sizeof(ush) * (size_t)N_NODES * 128);
    ush*    a2      = (ush*)   walloc(sizeof(ush) * (size_t)N_NODES * 128);
    short*  Wh3     = (short*) walloc(sizeof(short) * (size_t)3 * NB * 128 * 128);

    // Runtime chunk-size fallback: T chunk must fit in the remaining ws.
    // 20000 % chunk_n == 0 and chunk_n % 32 == 0 for all candidates.
    int chunk_n = 10000;
    {
        const int cand[3] = {10000, 4000, 2000};
        for (int i = 0; i < 3; i++) {
            size_t need = (size_t)cand[i] * TLD * sizeof(ush);
            chunk_n = cand[i];
            if (off + need <= ws_size) break;
        }
    }
    ush* T = (ush*)walloc((size_t)chunk_n * TLD * sizeof(ush));

    int* srcv = e32;
    int* dstv = e32 + E_EDGES;
    int* hist   = histcur;
    int* cursor = histcur + N_NODES;

    detect_kernel<<<1, 1024, 0, stream>>>((const unsigned int*)eix, flag);
    decode_edges<<<(2 * E_EDGES + 255) / 256, 256, 0, stream>>>(eix, flag, e32, 2 * E_EDGES);
    edge_basis<<<(E_EDGES + 255) / 256, 256, 0, stream>>>(ea, Wp1, bp1, Wp2, bp2, fb);

    // CSR binned by dst; hierarchical scan; built once, reused across 3 layers
    const int NBLK = (N_NODES + 255) / 256;    // 79
    zero_int<<<(N_NODES * 2 + 255) / 256, 256, 0, stream>>>(histcur, N_NODES * 2);
    hist_kernel<<<(E_EDGES + 255) / 256, 256, 0, stream>>>(dstv, hist);
    scan_blk<<<NBLK, 256, 0, stream>>>(hist, rowptr, bsum, N_NODES);
    scan_top<<<1, 256, 0, stream>>>(bsum, NBLK);
    scan_add<<<NBLK, 256, 0, stream>>>(rowptr, bsum, N_NODES);
    perm_kernel<<<(E_EDGES + 255) / 256, 256, 0, stream>>>(dstv, rowptr, cursor, eperm);
    pack_w27<<<(E_EDGES + 255) / 256, 256, 0, stream>>>(eperm, srcv, fb, srcp, w28p);

    packW3_kernel<<<(3 * NB * 4 * 8 * 64 + 255) / 256, 256, 0, stream>>>(
        W[0], Wr[0], W[1], Wr[1], W[2], Wr[2], Wh3);
    conv_xb<<<(N_NODES * CIN / 4 + 255) / 256, 256, 0, stream>>>(x, xb);

    const ush* actin = xb;
    for (int l = 0; l < 3; l++) {
        const short* Wh = Wh3 + (size_t)l * NB * 128 * 128;
        ush* actout = (l == 0) ? a1 : (l == 1) ? a2 : nullptr;
        for (int n0 = 0; n0 < N_NODES; n0 += chunk_n) {
            int cn = (n0 + chunk_n <= N_NODES) ? chunk_n : (N_NODES - n0);
            int nmt = cn / 16;
            accumT_kernel<<<(cn + 3) / 4, 256, 0, stream>>>(
                actin, rowptr, srcp, w28p, T, n0, n0 + cn);
            gemm2_kernel<<<nmt, 1024, 0, stream>>>(
                T, actin, Wh, b[l], actout, (l == 2) ? out : nullptr,
                n0, (l < 2) ? 1 : 0);
        }
        if (l == 0) actin = a1; else if (l == 1) actin = a2;
    }
}

// Round 12
// 629.048 us; speedup vs baseline: 1.1788x; 1.1788x over previous
//
#include <hip/hip_runtime.h>
#include <hip/hip_bf16.h>
#include <hip/hip_fp16.h>

#define N_NODES 20000
#define E_EDGES 320000
#define CIN 128
#define HDIM 128
#define EDGE_DIM 16
#define SDIM 3
#define KS 3
#define KK 27           // 3^3 kernel weight matrices
#define NB 28           // 27 spline blocks + 1 root-weight block
#define KSTEPS 112      // NB*128/32 k-steps of the fused GEMM
#define TLD (KK * 128)  // node-major T leading dim = 3456 shorts (root not stored)
#define WLD 28          // per-edge fp32 spline-weight stride (floats, 7 x float4)
#define MLP_HID 6

typedef __attribute__((ext_vector_type(8))) short v8s;   // 8 bf16 (4 VGPRs)
typedef __attribute__((ext_vector_type(4))) float v4f;   // MFMA accumulator
typedef unsigned short ush;

static __device__ __forceinline__ short f2bf(float v) {
    unsigned u = __float_as_uint(v);
    unsigned r = (u + 0x7fffu + ((u >> 16) & 1u)) >> 16;   // RTNE
    return (short)r;
}
static __device__ __forceinline__ float bf2f_lo(unsigned u) {   // low short
    return __uint_as_float(u << 16);
}
static __device__ __forceinline__ float bf2f_hi(unsigned u) {   // high short
    return __uint_as_float(u & 0xffff0000u);
}
static __device__ __forceinline__ unsigned pack2bf(float a, float b) {
    return ((unsigned)(ush)f2bf(a)) | (((unsigned)(ush)f2bf(b)) << 16);
}

// ---------------------------------------------------------------------------
// edge_index dtype detect + decode (int64 vs int32 storage)
// ---------------------------------------------------------------------------
__global__ void detect_kernel(const unsigned int* __restrict__ e, int* __restrict__ flag) {
    __shared__ int s_nz;
    if (threadIdx.x == 0) s_nz = 0;
    __syncthreads();
    unsigned int v = e[threadIdx.x * 2 + 1];
    if (v != 0) atomicAdd(&s_nz, 1);
    __syncthreads();
    if (threadIdx.x == 0) *flag = (s_nz > 0) ? 1 : 0;
}

__global__ void decode_edges(const void* __restrict__ eraw, const int* __restrict__ flag,
                             int* __restrict__ e32, int n) {
    int i = blockIdx.x * blockDim.x + threadIdx.x;
    if (i >= n) return;
    if (*flag) e32[i] = ((const int*)eraw)[i];
    else       e32[i] = (int)(((const long long*)eraw)[i]);
}

// ---------------------------------------------------------------------------
// Edge MLP (16->6 relu ->3 sigmoid) -> (frac[3], lo[3]) per edge, packed 16 B.
// ---------------------------------------------------------------------------
__global__ void edge_basis(const float* __restrict__ ea,
                           const float* __restrict__ Wp1, const float* __restrict__ bp1,
                           const float* __restrict__ Wp2, const float* __restrict__ bp2,
                           float4* __restrict__ fb) {
    __shared__ float sW1[EDGE_DIM * MLP_HID];
    __shared__ float sb1[MLP_HID];
    __shared__ float sW2[MLP_HID * SDIM];
    __shared__ float sb2[SDIM];
    int t = threadIdx.x;
    if (t < EDGE_DIM * MLP_HID) sW1[t] = Wp1[t];
    if (t < MLP_HID)            sb1[t] = bp1[t];
    if (t < MLP_HID * SDIM)     sW2[t] = Wp2[t];
    if (t < SDIM)               sb2[t] = bp2[t];
    __syncthreads();
    int e = blockIdx.x * blockDim.x + t;
    if (e >= E_EDGES) return;

    float a[EDGE_DIM];
#pragma unroll
    for (int i = 0; i < EDGE_DIM; i++) a[i] = ea[(long)e * EDGE_DIM + i];

    float hid[MLP_HID];
#pragma unroll
    for (int j = 0; j < MLP_HID; j++) {
        float s = sb1[j];
#pragma unroll
        for (int i = 0; i < EDGE_DIM; i++) s += a[i] * sW1[i * MLP_HID + j];
        hid[j] = fmaxf(s, 0.f);
    }

    float fr[SDIM];
    unsigned lp = 0;
#pragma unroll
    for (int d = 0; d < SDIM; d++) {
        float s = sb2[d];
#pragma unroll
        for (int j = 0; j < MLP_HID; j++) s += hid[j] * sW2[j * SDIM + d];
        float u = 1.f / (1.f + expf(-s));
        float v = u * (float)(KS - 1);
        float l = floorf(v);
        l = fminf(fmaxf(l, 0.f), (float)(KS - 2));
        fr[d] = v - l;
        lp |= ((unsigned)(int)l) << (8 * d);
    }
    float4 o;
    o.x = fr[0]; o.y = fr[1]; o.z = fr[2]; o.w = __uint_as_float(lp);
    fb[e] = o;
}

// ---------------------------------------------------------------------------
// CSR build binned by dst — built once, reused for 3 layers.
// Hierarchical 3-dispatch scan.
// ---------------------------------------------------------------------------
__global__ void zero_int(int* __restrict__ p, int n) {
    int i = blockIdx.x * blockDim.x + threadIdx.x;
    if (i < n) p[i] = 0;
}

__global__ void hist_kernel(const int* __restrict__ dst, int* __restrict__ hist) {
    int e = blockIdx.x * blockDim.x + threadIdx.x;
    if (e >= E_EDGES) return;
    atomicAdd(&hist[dst[e]], 1);
}

__global__ void scan_blk(const int* __restrict__ hist, int* __restrict__ rowptr,
                         int* __restrict__ bsum, int B) {
    __shared__ int sh[256];
    int i = blockIdx.x * 256 + threadIdx.x;
    int v = (i < B) ? hist[i] : 0;
    sh[threadIdx.x] = v;
    __syncthreads();
    for (int off = 1; off < 256; off <<= 1) {
        int t = (threadIdx.x >= off) ? sh[threadIdx.x - off] : 0;
        __syncthreads();
        sh[threadIdx.x] += t;
        __syncthreads();
    }
    if (i < B) rowptr[i] = sh[threadIdx.x] - v;        // block-local exclusive
    if (threadIdx.x == 255) bsum[blockIdx.x] = sh[255];
}

__global__ void scan_top(int* __restrict__ bsum, int nb) {
    __shared__ int sh[256];
    int v = (threadIdx.x < nb) ? bsum[threadIdx.x] : 0;
    sh[threadIdx.x] = v;
    __syncthreads();
    for (int off = 1; off < 256; off <<= 1) {
        int t = (threadIdx.x >= off) ? sh[threadIdx.x - off] : 0;
        __syncthreads();
        sh[threadIdx.x] += t;
        __syncthreads();
    }
    if (threadIdx.x < nb) bsum[threadIdx.x] = sh[threadIdx.x] - v;   // exclusive
}

__global__ void scan_add(int* __restrict__ rowptr, const int* __restrict__ bsum, int B) {
    int i = blockIdx.x * 256 + threadIdx.x;
    if (i < B) rowptr[i] += bsum[blockIdx.x];
    if (i == 0) rowptr[B] = E_EDGES;
}

__global__ void perm_kernel(const int* __restrict__ dst,
                            const int* __restrict__ rowptr, int* __restrict__ cursor,
                            int* __restrict__ eperm) {
    int e = blockIdx.x * blockDim.x + threadIdx.x;
    if (e >= E_EDGES) return;
    int bin = dst[e];
    int pos = rowptr[bin] + atomicAdd(&cursor[bin], 1);
    eperm[pos] = e;
}

// ---------------------------------------------------------------------------
// Pack per-edge metadata into CSR order: src index + DENSE 27 fp32 spline
// weights (stride 28 floats = 7 float4).
// ---------------------------------------------------------------------------
__global__ void pack_w27(const int* __restrict__ eperm, const int* __restrict__ src,
                         const float4* __restrict__ fb,
                         int* __restrict__ srcp, float* __restrict__ w28p) {
    int j = blockIdx.x * blockDim.x + threadIdx.x;
    if (j >= E_EDGES) return;
    int e = eperm[j];
    srcp[j] = src[e];
    float4 f = fb[e];
    unsigned lp = __float_as_uint(f.w);
    float fr[3] = {f.x, f.y, f.z};
    float t[3][3];
#pragma unroll
    for (int d = 0; d < 3; d++) {
        int lo = (lp >> (8 * d)) & 255;
        float fd = fr[d];
#pragma unroll
        for (int q = 0; q < 3; q++)
            t[d][q] = (q == lo) ? (1.f - fd) : (q == lo + 1) ? fd : 0.f;
    }
    float out[WLD];
#pragma unroll
    for (int k2 = 0; k2 < 3; k2++)
#pragma unroll
        for (int k1 = 0; k1 < 3; k1++)
#pragma unroll
            for (int k0 = 0; k0 < 3; k0++)
                out[k2 * 9 + k1 * 3 + k0] = t[0][k0] * t[1][k1] * t[2][k2];
    out[27] = 0.f;
    float* op = w28p + (size_t)j * WLD;
#pragma unroll
    for (int q = 0; q < WLD / 4; q++) *(float4*)(op + 4 * q) = *(float4*)(out + 4 * q);
}

// ---------------------------------------------------------------------------
// Pack [W (27 blocks) | Wr] of ALL 3 LAYERS -> bf16 MFMA B-fragment layout.
// Layout [layer][flat_ks=kb*4+ks][nt][64][8] — one fused K=3584 B panel.
// ---------------------------------------------------------------------------
__global__ void packW3_kernel(const float* __restrict__ W0, const float* __restrict__ Wr0,
                              const float* __restrict__ W1, const float* __restrict__ Wr1,
                              const float* __restrict__ W2, const float* __restrict__ Wr2,
                              short* __restrict__ hi) {
    int gid = blockIdx.x * blockDim.x + threadIdx.x;
    if (gid >= 3 * NB * 4 * 8 * 64) return;
    int lane = gid & 63;
    int nt = (gid >> 6) & 7;
    int ks = (gid >> 9) & 3;
    int kb2 = gid >> 11;           // 0..83
    int layer = kb2 / NB;
    int kb = kb2 - layer * NB;
    const float* W  = (layer == 0) ? W0  : (layer == 1) ? W1  : W2;
    const float* Wr = (layer == 0) ? Wr0 : (layer == 1) ? Wr1 : Wr2;
    int i0 = ks * 32 + ((lane >> 4) & 3) * 8;
    int o = nt * 16 + (lane & 15);
    const float* src = (kb < KK) ? (W + (long)kb * 16384 + (long)i0 * 128 + o)
                                 : (Wr + (long)i0 * 128 + o);
    long off = ((long)(((size_t)layer * NB + kb) * 4 + ks) * 8 + nt) * 64 * 8
             + (long)lane * 8;
#pragma unroll
    for (int j = 0; j < 8; j++) {
        float v = src[(long)j * 128];
        hi[off + j] = f2bf(v);
    }
}

// ---------------------------------------------------------------------------
// x (fp32) -> xb (bf16 row-major) once; later layers' activations are written
// bf16 row-major by the GEMM epilogue directly.
// ---------------------------------------------------------------------------
__global__ void conv_xb(const float* __restrict__ x, ush* __restrict__ xb) {
    int i = blockIdx.x * blockDim.x + threadIdx.x;
    if (i >= N_NODES * CIN / 4) return;
    float4 v = ((const float4*)x)[i];
    uint2 d;
    d.x = pack2bf(v.x, v.y);
    d.y = pack2bf(v.z, v.w);
    ((uint2*)xb)[i] = d;
}

// ---------------------------------------------------------------------------
// accumT v8: 4 WAVES PER 256-THREAD BLOCK, ONE NODE PER WAVE, with EXPLICIT
// per-wave scalarization. R11 lesson: `n = f(threadIdx.x>>6)` defeats the
// compiler's uniformity analysis (SGPR 112->32, VGPR 36->100, occupancy
// 16%) — the weight pipeline fell out of the scalar pipe into VGPRs.
// readfirstlane(jb/je) is a semantic no-op (all lanes of a wave share n)
// but re-establishes provable wave-uniformity: metadata loads return to
// s_load / SGPR slots, VGPR count drops back, and the 256-thread workgroup
// lifts the residency cap from ~10 waves/CU (64-thr dispatch limit) toward
// the 32-wave hardware cap — TLP hides the SMEM drain stalls.
// Per-wave code otherwise identical to v6 (depth-4 slots, depth-8 srcp).
// ---------------------------------------------------------------------------
__global__ __launch_bounds__(256) void accumT_kernel(
    const ush* __restrict__ act, const int* __restrict__ rowptr,
    const int* __restrict__ srcp, const float* __restrict__ w28p,
    ush* __restrict__ T, int n0, int nmax)
{
    int lane = threadIdx.x & 63;
    int wave = threadIdx.x >> 6;
    int n = n0 + blockIdx.x * 4 + wave;
    if (n >= nmax) return;
    int jb = __builtin_amdgcn_readfirstlane(rowptr[n]);
    int je = __builtin_amdgcn_readfirstlane(rowptr[n + 1]);

    float acc[KK][2];
#pragma unroll
    for (int k = 0; k < KK; k++) { acc[k][0] = 0.f; acc[k][1] = 0.f; }

    const ush* actl = act + lane * 2;                 // channel-pair base
    const float4* w4 = (const float4*)w28p;           // stride 7 per edge

    if (jb < je) {
        int last = je - 1;
        unsigned xs[4];
        float4 ws[4][7];
        int sn[4];
        // fill slots with edges jb..jb+3 (clamped); preload srcs of jb+4..jb+7
#pragma unroll
        for (int q = 0; q < 4; q++) {
            int jq = (jb + q > last) ? last : jb + q;
            int s = srcp[jq];
            xs[q] = *(const unsigned*)(actl + (size_t)s * 128);
#pragma unroll
            for (int t = 0; t < 7; t++) ws[q][t] = w4[(size_t)jq * 7 + t];
            int jf = (jb + 4 + q > last) ? last : jb + 4 + q;
            sn[q] = srcp[jf];
        }

        for (int j = jb; j < je; j += 4) {
#pragma unroll
            for (int s = 0; s < 4; s++) {
                if (s == 0 || j + s < je) {           // wave-uniform guard
                    float x0 = bf2f_lo(xs[s]), x1 = bf2f_hi(xs[s]);
                    float w[28];
#pragma unroll
                    for (int t = 0; t < 7; t++) *(float4*)(w + 4 * t) = ws[s][t];
#pragma unroll
                    for (int k = 0; k < KK; k++) {
                        acc[k][0] += w[k] * x0;
                        acc[k][1] += w[k] * x1;
                    }
                }
                // refill slot s <- edge j+4+s (clamped; never computed if pad)
                int jn = (j + 4 + s > last) ? last : j + 4 + s;
                xs[s] = *(const unsigned*)(actl + (size_t)sn[s] * 128);
#pragma unroll
                for (int t = 0; t < 7; t++) ws[s][t] = w4[(size_t)jn * 7 + t];
                int jf = (j + 8 + s > last) ? last : j + 8 + s;
                sn[s] = srcp[jf];
            }
        }
    }

    ush* tp = T + (size_t)(n - n0) * TLD + lane * 2;
#pragma unroll
    for (int k = 0; k < KK; k++) {
        *(unsigned*)(tp + (size_t)k * 128) = pack2bf(acc[k][0], acc[k][1]);
    }
}

// ---------------------------------------------------------------------------
// gemm2 v8 (unchanged from R10): 1024 threads / 16 waves, ONE m-tile per
// block -> 625 fine-grained blocks. Wave owns 7 k-steps, fully unrolled.
// 16-way cross-wave reduce via LDS (69.6 KB) in 2 passes.
// ---------------------------------------------------------------------------
__global__ __launch_bounds__(1024) void gemm2_kernel(
    const ush* __restrict__ T, const ush* __restrict__ act,
    const short* __restrict__ Wh, const float* __restrict__ bias,
    ush* __restrict__ actout, float* __restrict__ fout,
    int n0, int relu)
{
    __shared__ float S[1024][17];
    int lane = threadIdx.x & 63;
    int wave = threadIdx.x >> 6;               // k-slice 0..15
    int mtr = blockIdx.x;

    v4f acc[8];
#pragma unroll
    for (int nt = 0; nt < 8; nt++) acc[nt] = (v4f){0.f, 0.f, 0.f, 0.f};

    int r15 = lane & 15;
    int sub = (lane >> 4) & 3;
    int arow = mtr * 16 + r15;                 // chunk-local row
    const ush* tp = T + (size_t)arow * TLD + sub * 8;
    const ush* ap = act + (size_t)(n0 + arow) * 128 + sub * 8;

    int ks0 = wave * (KSTEPS / 16);            // 7 k-steps per wave
#pragma unroll
    for (int i = 0; i < KSTEPS / 16; i++) {
        int ks = ks0 + i;
        v8s a = (ks < KK * 4) ? *(const v8s*)(tp + ks * 32)
                              : *(const v8s*)(ap + (ks - KK * 4) * 32);
        const short* wb = Wh + (size_t)ks * 4096 + (size_t)lane * 8;
#pragma unroll
        for (int nt = 0; nt < 8; nt++) {
            v8s b = *(const v8s*)(wb + (size_t)nt * 512);
            acc[nt] = __builtin_amdgcn_mfma_f32_16x16x32_bf16(a, b, acc[nt], 0, 0, 0);
        }
    }

    // 16-way cross-wave reduce + epilogue: 2 passes (2 column halves)
    int r  = threadIdx.x >> 6;                 // output row in m-tile (0..15)
    int cl = threadIdx.x & 63;                 // column within the 64-col half
    int row = n0 + mtr * 16 + r;
#pragma unroll
    for (int p = 0; p < 2; p++) {
        __syncthreads();
#pragma unroll
        for (int q = 0; q < 16; q++)
            S[threadIdx.x][q] = acc[p * 4 + (q >> 2)][q & 3];
        __syncthreads();
        int c = p * 64 + cl;                   // global output column
        int ln  = (cl & 15) + 16 * (r >> 2);   // source lane of C-frag
        int idx = (cl >> 4) * 4 + (r & 3);     // nt_local*4 + reg
        float s = 0.f;
#pragma unroll
        for (int w = 0; w < 16; w++) s += S[w * 64 + ln][idx];
        s += bias[c];
        if (relu) s = fmaxf(s, 0.f);
        if (actout) {
            actout[(size_t)row * 128 + c] = (ush)f2bf(s);
        } else {
            fout[(size_t)row * 128 + c] = s;
        }
    }
}

// ---------------------------------------------------------------------------
extern "C" void kernel_launch(void* const* d_in, const int* in_sizes, int n_in,
                              void* d_out, int out_size, void* d_ws, size_t ws_size,
                              hipStream_t stream) {
    const float* x   = (const float*)d_in[0];
    const void*  eix = d_in[1];
    const float* ea  = (const float*)d_in[2];
    const float* Wp1 = (const float*)d_in[3];
    const float* bp1 = (const float*)d_in[4];
    const float* Wp2 = (const float*)d_in[5];
    const float* bp2 = (const float*)d_in[6];
    const float* W[3]  = {(const float*)d_in[7],  (const float*)d_in[10], (const float*)d_in[13]};
    const float* Wr[3] = {(const float*)d_in[8],  (const float*)d_in[11], (const float*)d_in[14]};
    const float* b[3]  = {(const float*)d_in[9],  (const float*)d_in[12], (const float*)d_in[15]};
    float* out = (float*)d_out;

    char* ws = (char*)d_ws;
    size_t off = 0;
    auto walloc = [&](size_t bytes) -> void* {
        void* p = ws + off;
        off = (off + bytes + 255) & ~(size_t)255;
        return p;
    };
    int*    flag    = (int*)   walloc(sizeof(int));
    int*    e32     = (int*)   walloc(sizeof(int) * 2 * E_EDGES);
    float4* fb      = (float4*)walloc(sizeof(float4) * (size_t)E_EDGES);
    int*    srcp    = (int*)   walloc(sizeof(int) * E_EDGES);
    int*    eperm   = (int*)   walloc(sizeof(int) * E_EDGES);
    float*  w28p    = (float*) walloc(sizeof(float) * (size_t)E_EDGES * WLD);
    int*    histcur = (int*)   walloc(sizeof(int) * (size_t)N_NODES * 2);
    int*    rowptr  = (int*)   walloc(sizeof(int) * (N_NODES + 1));
    int*    bsum    = (int*)   walloc(sizeof(int) * 256);
    ush*    xb      = (ush*)   walloc(sizeof(ush) * (size_t)N_NODES * 128);
    ush*    a1      = (ush*)   walloc(sizeof(ush) * (size_t)N_NODES * 128);
    ush*    a2      = (ush*)   walloc(sizeof(ush) * (size_t)N_NODES * 128);
    short*  Wh3     = (short*) walloc(sizeof(short) * (size_t)3 * NB * 128 * 128);

    // Runtime chunk-size fallback: T chunk must fit in the remaining ws.
    // 20000 % chunk_n == 0 and chunk_n % 32 == 0 for all candidates.
    int chunk_n = 10000;
    {
        const int cand[3] = {10000, 4000, 2000};
        for (int i = 0; i < 3; i++) {
            size_t need = (size_t)cand[i] * TLD * sizeof(ush);
            chunk_n = cand[i];
            if (off + need <= ws_size) break;
        }
    }
    ush* T = (ush*)walloc((size_t)chunk_n * TLD * sizeof(ush));

    int* srcv = e32;
    int* dstv = e32 + E_EDGES;
    int* hist   = histcur;
    int* cursor = histcur + N_NODES;

    detect_kernel<<<1, 1024, 0, stream>>>((const unsigned int*)eix, flag);
    decode_edges<<<(2 * E_EDGES + 255) / 256, 256, 0, stream>>>(eix, flag, e32, 2 * E_EDGES);
    edge_basis<<<(E_EDGES + 255) / 256, 256, 0, stream>>>(ea, Wp1, bp1, Wp2, bp2, fb);

    // CSR binned by dst; hierarchical scan; built once, reused across 3 layers
    const int NBLK = (N_NODES + 255) / 256;    // 79
    zero_int<<<(N_NODES * 2 + 255) / 256, 256, 0, stream>>>(histcur, N_NODES * 2);
    hist_kernel<<<(E_EDGES + 255) / 256, 256, 0, stream>>>(dstv, hist);
    scan_blk<<<NBLK, 256, 0, stream>>>(hist, rowptr, bsum, N_NODES);
    scan_top<<<1, 256, 0, stream>>>(bsum, NBLK);
    scan_add<<<NBLK, 256, 0, stream>>>(rowptr, bsum, N_NODES);
    perm_kernel<<<(E_EDGES + 255) / 256, 256, 0, stream>>>(dstv, rowptr, cursor, eperm);
    pack_w27<<<(E_EDGES + 255) / 256, 256, 0, stream>>>(eperm, srcv, fb, srcp, w28p);

    packW3_kernel<<<(3 * NB * 4 * 8 * 64 + 255) / 256, 256, 0, stream>>>(
        W[0], Wr[0], W[1], Wr[1], W[2], Wr[2], Wh3);
    conv_xb<<<(N_NODES * CIN / 4 + 255) / 256, 256, 0, stream>>>(x, xb);

    const ush* actin = xb;
    for (int l = 0; l < 3; l++) {
        const short* Wh = Wh3 + (size_t)l * NB * 128 * 128;
        ush* actout = (l == 0) ? a1 : (l == 1) ? a2 : nullptr;
        for (int n0 = 0; n0 < N_NODES; n0 += chunk_n) {
            int cn = (n0 + chunk_n <= N_NODES) ? chunk_n : (N_NODES - n0);
            int nmt = cn / 16;
            accumT_kernel<<<(cn + 3) / 4, 256, 0, stream>>>(
                actin, rowptr, srcp, w28p, T, n0, n0 + cn);
            gemm2_kernel<<<nmt, 1024, 0, stream>>>(
                T, actin, Wh, b[l], actout, (l == 2) ? out : nullptr,
                n0, (l < 2) ? 1 : 0);
        }
        if (l == 0) actin = a1; else if (l == 1) actin = a2;
    }
}

// Round 13
// 526.792 us; speedup vs baseline: 1.4076x; 1.1941x over previous
//
#include <hip/hip_runtime.h>
#include <hip/hip_bf16.h>
#include <hip/hip_fp16.h>

#define N_NODES 20000
#define E_EDGES 320000
#define CIN 128
#define HDIM 128
#define EDGE_DIM 16
#define SDIM 3
#define KS 3
#define KK 27           // 3^3 kernel weight matrices
#define NB 28           // 27 spline blocks + 1 root-weight block
#define KSTEPS 112      // NB*128/32 k-steps of the fused GEMM
#define TLD (KK * 128)  // node-major T leading dim = 3456 shorts (root not stored)
#define RLD 32          // per-edge record stride (floats): [srcp|pad3|w27|pad] = 128 B
#define EPAD 8          // zero-padded tail records
#define MLP_HID 6

typedef __attribute__((ext_vector_type(8))) short v8s;   // 8 bf16 (4 VGPRs)
typedef __attribute__((ext_vector_type(4))) float v4f;   // MFMA accumulator
typedef unsigned short ush;

static __device__ __forceinline__ short f2bf(float v) {
    unsigned u = __float_as_uint(v);
    unsigned r = (u + 0x7fffu + ((u >> 16) & 1u)) >> 16;   // RTNE
    return (short)r;
}
static __device__ __forceinline__ float bf2f_lo(unsigned u) {   // low short
    return __uint_as_float(u << 16);
}
static __device__ __forceinline__ float bf2f_hi(unsigned u) {   // high short
    return __uint_as_float(u & 0xffff0000u);
}
static __device__ __forceinline__ unsigned pack2bf(float a, float b) {
    return ((unsigned)(ush)f2bf(a)) | (((unsigned)(ush)f2bf(b)) << 16);
}

// ---------------------------------------------------------------------------
// edge_index dtype detect + decode (int64 vs int32 storage)
// ---------------------------------------------------------------------------
__global__ void detect_kernel(const unsigned int* __restrict__ e, int* __restrict__ flag) {
    __shared__ int s_nz;
    if (threadIdx.x == 0) s_nz = 0;
    __syncthreads();
    unsigned int v = e[threadIdx.x * 2 + 1];
    if (v != 0) atomicAdd(&s_nz, 1);
    __syncthreads();
    if (threadIdx.x == 0) *flag = (s_nz > 0) ? 1 : 0;
}

__global__ void decode_edges(const void* __restrict__ eraw, const int* __restrict__ flag,
                             int* __restrict__ e32, int n) {
    int i = blockIdx.x * blockDim.x + threadIdx.x;
    if (i >= n) return;
    if (*flag) e32[i] = ((const int*)eraw)[i];
    else       e32[i] = (int)(((const long long*)eraw)[i]);
}

// ---------------------------------------------------------------------------
// Edge MLP (16->6 relu ->3 sigmoid) -> (frac[3], lo[3]) per edge, packed 16 B.
// ---------------------------------------------------------------------------
__global__ void edge_basis(const float* __restrict__ ea,
                           const float* __restrict__ Wp1, const float* __restrict__ bp1,
                           const float* __restrict__ Wp2, const float* __restrict__ bp2,
                           float4* __restrict__ fb) {
    __shared__ float sW1[EDGE_DIM * MLP_HID];
    __shared__ float sb1[MLP_HID];
    __shared__ float sW2[MLP_HID * SDIM];
    __shared__ float sb2[SDIM];
    int t = threadIdx.x;
    if (t < EDGE_DIM * MLP_HID) sW1[t] = Wp1[t];
    if (t < MLP_HID)            sb1[t] = bp1[t];
    if (t < MLP_HID * SDIM)     sW2[t] = Wp2[t];
    if (t < SDIM)               sb2[t] = bp2[t];
    __syncthreads();
    int e = blockIdx.x * blockDim.x + t;
    if (e >= E_EDGES) return;

    float a[EDGE_DIM];
#pragma unroll
    for (int i = 0; i < EDGE_DIM; i++) a[i] = ea[(long)e * EDGE_DIM + i];

    float hid[MLP_HID];
#pragma unroll
    for (int j = 0; j < MLP_HID; j++) {
        float s = sb1[j];
#pragma unroll
        for (int i = 0; i < EDGE_DIM; i++) s += a[i] * sW1[i * MLP_HID + j];
        hid[j] = fmaxf(s, 0.f);
    }

    float fr[SDIM];
    unsigned lp = 0;
#pragma unroll
    for (int d = 0; d < SDIM; d++) {
        float s = sb2[d];
#pragma unroll
        for (int j = 0; j < MLP_HID; j++) s += hid[j] * sW2[j * SDIM + d];
        float u = 1.f / (1.f + expf(-s));
        float v = u * (float)(KS - 1);
        float l = floorf(v);
        l = fminf(fmaxf(l, 0.f), (float)(KS - 2));
        fr[d] = v - l;
        lp |= ((unsigned)(int)l) << (8 * d);
    }
    float4 o;
    o.x = fr[0]; o.y = fr[1]; o.z = fr[2]; o.w = __uint_as_float(lp);
    fb[e] = o;
}

// ---------------------------------------------------------------------------
// CSR build binned by dst — built once, reused for 3 layers.
// Hierarchical 3-dispatch scan.
// ---------------------------------------------------------------------------
__global__ void zero_int(int* __restrict__ p, int n) {
    int i = blockIdx.x * blockDim.x + threadIdx.x;
    if (i < n) p[i] = 0;
}

__global__ void hist_kernel(const int* __restrict__ dst, int* __restrict__ hist) {
    int e = blockIdx.x * blockDim.x + threadIdx.x;
    if (e >= E_EDGES) return;
    atomicAdd(&hist[dst[e]], 1);
}

__global__ void scan_blk(const int* __restrict__ hist, int* __restrict__ rowptr,
                         int* __restrict__ bsum, int B) {
    __shared__ int sh[256];
    int i = blockIdx.x * 256 + threadIdx.x;
    int v = (i < B) ? hist[i] : 0;
    sh[threadIdx.x] = v;
    __syncthreads();
    for (int off = 1; off < 256; off <<= 1) {
        int t = (threadIdx.x >= off) ? sh[threadIdx.x - off] : 0;
        __syncthreads();
        sh[threadIdx.x] += t;
        __syncthreads();
    }
    if (i < B) rowptr[i] = sh[threadIdx.x] - v;        // block-local exclusive
    if (threadIdx.x == 255) bsum[blockIdx.x] = sh[255];
}

__global__ void scan_top(int* __restrict__ bsum, int nb) {
    __shared__ int sh[256];
    int v = (threadIdx.x < nb) ? bsum[threadIdx.x] : 0;
    sh[threadIdx.x] = v;
    __syncthreads();
    for (int off = 1; off < 256; off <<= 1) {
        int t = (threadIdx.x >= off) ? sh[threadIdx.x - off] : 0;
        __syncthreads();
        sh[threadIdx.x] += t;
        __syncthreads();
    }
    if (threadIdx.x < nb) bsum[threadIdx.x] = sh[threadIdx.x] - v;   // exclusive
}

__global__ void scan_add(int* __restrict__ rowptr, const int* __restrict__ bsum, int B) {
    int i = blockIdx.x * 256 + threadIdx.x;
    if (i < B) rowptr[i] += bsum[blockIdx.x];
    if (i == 0) rowptr[B] = E_EDGES;
}

__global__ void perm_kernel(const int* __restrict__ dst,
                            const int* __restrict__ rowptr, int* __restrict__ cursor,
                            int* __restrict__ eperm) {
    int e = blockIdx.x * blockDim.x + threadIdx.x;
    if (e >= E_EDGES) return;
    int bin = dst[e];
    int pos = rowptr[bin] + atomicAdd(&cursor[bin], 1);
    eperm[pos] = e;
}

// ---------------------------------------------------------------------------
// Pack per-edge metadata into CSR order as 128-B records:
// float[32] = [ srcp(bits) | pad x3 | w27[0..26] | pad ].
// Weights at 16B-aligned offsets 16..128 -> 7x float4 reads.
// Records >= E_EDGES are zeroed (srcp=0, w=0): staged tail batches are
// harmless (0-weight) and index 0 is always a valid act row.
// ---------------------------------------------------------------------------
__global__ void pack_rec(const int* __restrict__ eperm, const int* __restrict__ src,
                         const float4* __restrict__ fb, float* __restrict__ rec) {
    int j = blockIdx.x * blockDim.x + threadIdx.x;
    if (j >= E_EDGES + EPAD) return;
    float out[RLD];
#pragma unroll
    for (int q = 0; q < RLD; q++) out[q] = 0.f;
    if (j < E_EDGES) {
        int e = eperm[j];
        out[0] = __int_as_float(src[e]);
        float4 f = fb[e];
        unsigned lp = __float_as_uint(f.w);
        float fr[3] = {f.x, f.y, f.z};
        float t[3][3];
#pragma unroll
        for (int d = 0; d < 3; d++) {
            int lo = (lp >> (8 * d)) & 255;
            float fd = fr[d];
#pragma unroll
            for (int q = 0; q < 3; q++)
                t[d][q] = (q == lo) ? (1.f - fd) : (q == lo + 1) ? fd : 0.f;
        }
#pragma unroll
        for (int k2 = 0; k2 < 3; k2++)
#pragma unroll
            for (int k1 = 0; k1 < 3; k1++)
#pragma unroll
                for (int k0 = 0; k0 < 3; k0++)
                    out[4 + k2 * 9 + k1 * 3 + k0] = t[0][k0] * t[1][k1] * t[2][k2];
    }
    float* op = rec + (size_t)j * RLD;
#pragma unroll
    for (int q = 0; q < RLD / 4; q++) *(float4*)(op + 4 * q) = *(float4*)(out + 4 * q);
}

// ---------------------------------------------------------------------------
// Pack [W (27 blocks) | Wr] of ALL 3 LAYERS -> bf16 MFMA B-fragment layout.
// Layout [layer][flat_ks=kb*4+ks][nt][64][8] — one fused K=3584 B panel.
// ---------------------------------------------------------------------------
__global__ void packW3_kernel(const float* __restrict__ W0, const float* __restrict__ Wr0,
                              const float* __restrict__ W1, const float* __restrict__ Wr1,
                              const float* __restrict__ W2, const float* __restrict__ Wr2,
                              short* __restrict__ hi) {
    int gid = blockIdx.x * blockDim.x + threadIdx.x;
    if (gid >= 3 * NB * 4 * 8 * 64) return;
    int lane = gid & 63;
    int nt = (gid >> 6) & 7;
    int ks = (gid >> 9) & 3;
    int kb2 = gid >> 11;           // 0..83
    int layer = kb2 / NB;
    int kb = kb2 - layer * NB;
    const float* W  = (layer == 0) ? W0  : (layer == 1) ? W1  : W2;
    const float* Wr = (layer == 0) ? Wr0 : (layer == 1) ? Wr1 : Wr2;
    int i0 = ks * 32 + ((lane >> 4) & 3) * 8;
    int o = nt * 16 + (lane & 15);
    const float* src = (kb < KK) ? (W + (long)kb * 16384 + (long)i0 * 128 + o)
                                 : (Wr + (long)i0 * 128 + o);
    long off = ((long)(((size_t)layer * NB + kb) * 4 + ks) * 8 + nt) * 64 * 8
             + (long)lane * 8;
#pragma unroll
    for (int j = 0; j < 8; j++) {
        float v = src[(long)j * 128];
        hi[off + j] = f2bf(v);
    }
}

// ---------------------------------------------------------------------------
// x (fp32) -> xb (bf16 row-major) once; later layers' activations are written
// bf16 row-major by the GEMM epilogue directly.
// ---------------------------------------------------------------------------
__global__ void conv_xb(const float* __restrict__ x, ush* __restrict__ xb) {
    int i = blockIdx.x * blockDim.x + threadIdx.x;
    if (i >= N_NODES * CIN / 4) return;
    float4 v = ((const float4*)x)[i];
    uint2 d;
    d.x = pack2bf(v.x, v.y);
    d.y = pack2bf(v.z, v.w);
    ((uint2*)xb)[i] = d;
}

// ---------------------------------------------------------------------------
// accumT v9: ONE NODE PER 64-THREAD BLOCK (uniformity automatic), metadata
// moved OFF the scalar pipe. R10/R12 lesson: the weight stream as s_loads is
// un-pipelinable — SMEM completes out-of-order, so consuming ANY s_load
// forces lgkmcnt(0), draining all prefetches (depth-2 = depth-4 = 42 us,
// VALUBusy 35% = pure FMA floor + exposed SMEM latency).
// New path: 8-edge record batches staged global->VGPR->LDS (vmcnt-COUNTED)
// into a private 2x1KB double buffer; srcp + weights then read back with
// ds_read (LDS is IN-ORDER -> counted lgkmcnt, ~10 cyc); act rows issued a
// full batch's worth up front (vmcnt-counted, depth 8). No SMEM in the hot
// loop => no drains; every wait targets an op issued >=1 batch (~1300 cyc)
// earlier. T written node-major, full 256 B coalesced lines per (n,k).
// ---------------------------------------------------------------------------
__global__ __launch_bounds__(64) void accumT_kernel(
    const ush* __restrict__ act, const int* __restrict__ rowptr,
    const float* __restrict__ rec, ush* __restrict__ T, int n0)
{
    __shared__ float lb[2][256];           // 2 x 1024 B batch slots
    int lane = threadIdx.x;
    int n = n0 + blockIdx.x;
    int jb = rowptr[n], je = rowptr[n + 1];
    int d = je - jb;

    float acc[KK][2];
#pragma unroll
    for (int k = 0; k < KK; k++) { acc[k][0] = 0.f; acc[k][1] = 0.f; }

    const ush* actl = act + lane * 2;                 // channel-pair base

    if (d > 0) {
        int nb = (d + 7) >> 3;                        // 8-edge batches
        const float4* rb = (const float4*)rec + (size_t)jb * 8;

        // prologue: stage batch 0, preload batch 1
        float4 g = rb[lane];
        *(float4*)(&lb[0][lane * 4]) = g;             // ds_write_b128
        if (nb > 1) g = rb[(size_t)64 + lane];

        for (int b = 0; b < nb; ++b) {
            int slot = b & 1;
            // stage batch b+1 into the other slot (its old content, batch
            // b-1, was consumed last iteration; DS is in-order per wave).
            if (b + 1 < nb) *(float4*)(&lb[slot ^ 1][lane * 4]) = g;
            if (b + 2 < nb) g = rb[(size_t)(b + 2) * 64 + lane];

            // batch-front: read 8 srcp (LDS broadcast), issue 8 act loads
            int sidx[8];
#pragma unroll
            for (int e = 0; e < 8; e++)
                sidx[e] = __float_as_int(lb[slot][e * 32]);
            unsigned xa[8];
#pragma unroll
            for (int e = 0; e < 8; e++)
                xa[e] = *(const unsigned*)(actl + (size_t)sidx[e] * 128);

            int rem = d - (b << 3);                   // valid edges this batch
#pragma unroll
            for (int e = 0; e < 8; e++) {
                if (e < rem) {                        // wave-uniform guard
                    float w[28];
#pragma unroll
                    for (int q = 0; q < 7; q++)
                        *(float4*)(w + 4 * q) =
                            *(const float4*)(&lb[slot][e * 32 + 4 + 4 * q]);
                    float x0 = bf2f_lo(xa[e]), x1 = bf2f_hi(xa[e]);
#pragma unroll
                    for (int k = 0; k < KK; k++) {
                        acc[k][0] += w[k] * x0;
                        acc[k][1] += w[k] * x1;
                    }
                }
            }
        }
    }

    ush* tp = T + (size_t)(n - n0) * TLD + lane * 2;
#pragma unroll
    for (int k = 0; k < KK; k++) {
        *(unsigned*)(tp + (size_t)k * 128) = pack2bf(acc[k][0], acc[k][1]);
    }
}

// ---------------------------------------------------------------------------
// gemm2 v8 (unchanged from R10): 1024 threads / 16 waves, ONE m-tile per
// block -> fine-grained blocks. Wave owns 7 k-steps, fully unrolled.
// 16-way cross-wave reduce via LDS (69.6 KB) in 2 passes.
// ---------------------------------------------------------------------------
__global__ __launch_bounds__(1024) void gemm2_kernel(
    const ush* __restrict__ T, const ush* __restrict__ act,
    const short* __restrict__ Wh, const float* __restrict__ bias,
    ush* __restrict__ actout, float* __restrict__ fout,
    int n0, int relu)
{
    __shared__ float S[1024][17];
    int lane = threadIdx.x & 63;
    int wave = threadIdx.x >> 6;               // k-slice 0..15
    int mtr = blockIdx.x;

    v4f acc[8];
#pragma unroll
    for (int nt = 0; nt < 8; nt++) acc[nt] = (v4f){0.f, 0.f, 0.f, 0.f};

    int r15 = lane & 15;
    int sub = (lane >> 4) & 3;
    int arow = mtr * 16 + r15;                 // chunk-local row
    const ush* tp = T + (size_t)arow * TLD + sub * 8;
    const ush* ap = act + (size_t)(n0 + arow) * 128 + sub * 8;

    int ks0 = wave * (KSTEPS / 16);            // 7 k-steps per wave
#pragma unroll
    for (int i = 0; i < KSTEPS / 16; i++) {
        int ks = ks0 + i;
        v8s a = (ks < KK * 4) ? *(const v8s*)(tp + ks * 32)
                              : *(const v8s*)(ap + (ks - KK * 4) * 32);
        const short* wb = Wh + (size_t)ks * 4096 + (size_t)lane * 8;
#pragma unroll
        for (int nt = 0; nt < 8; nt++) {
            v8s b = *(const v8s*)(wb + (size_t)nt * 512);
            acc[nt] = __builtin_amdgcn_mfma_f32_16x16x32_bf16(a, b, acc[nt], 0, 0, 0);
        }
    }

    // 16-way cross-wave reduce + epilogue: 2 passes (2 column halves)
    int r  = threadIdx.x >> 6;                 // output row in m-tile (0..15)
    int cl = threadIdx.x & 63;                 // column within the 64-col half
    int row = n0 + mtr * 16 + r;
#pragma unroll
    for (int p = 0; p < 2; p++) {
        __syncthreads();
#pragma unroll
        for (int q = 0; q < 16; q++)
            S[threadIdx.x][q] = acc[p * 4 + (q >> 2)][q & 3];
        __syncthreads();
        int c = p * 64 + cl;                   // global output column
        int ln  = (cl & 15) + 16 * (r >> 2);   // source lane of C-frag
        int idx = (cl >> 4) * 4 + (r & 3);     // nt_local*4 + reg
        float s = 0.f;
#pragma unroll
        for (int w = 0; w < 16; w++) s += S[w * 64 + ln][idx];
        s += bias[c];
        if (relu) s = fmaxf(s, 0.f);
        if (actout) {
            actout[(size_t)row * 128 + c] = (ush)f2bf(s);
        } else {
            fout[(size_t)row * 128 + c] = s;
        }
    }
}

// ---------------------------------------------------------------------------
extern "C" void kernel_launch(void* const* d_in, const int* in_sizes, int n_in,
                              void* d_out, int out_size, void* d_ws, size_t ws_size,
                              hipStream_t stream) {
    const float* x   = (const float*)d_in[0];
    const void*  eix = d_in[1];
    const float* ea  = (const float*)d_in[2];
    const float* Wp1 = (const float*)d_in[3];
    const float* bp1 = (const float*)d_in[4];
    const float* Wp2 = (const float*)d_in[5];
    const float* bp2 = (const float*)d_in[6];
    const float* W[3]  = {(const float*)d_in[7],  (const float*)d_in[10], (const float*)d_in[13]};
    const float* Wr[3] = {(const float*)d_in[8],  (const float*)d_in[11], (const float*)d_in[14]};
    const float* b[3]  = {(const float*)d_in[9],  (const float*)d_in[12], (const float*)d_in[15]};
    float* out = (float*)d_out;

    char* ws = (char*)d_ws;
    size_t off = 0;
    auto walloc = [&](size_t bytes) -> void* {
        void* p = ws + off;
        off = (off + bytes + 255) & ~(size_t)255;
        return p;
    };
    int*    flag    = (int*)   walloc(sizeof(int));
    int*    e32     = (int*)   walloc(sizeof(int) * 2 * E_EDGES);
    float4* fb      = (float4*)walloc(sizeof(float4) * (size_t)E_EDGES);
    int*    eperm   = (int*)   walloc(sizeof(int) * E_EDGES);
    float*  rec     = (float*) walloc(sizeof(float) * (size_t)(E_EDGES + EPAD) * RLD);
    int*    histcur = (int*)   walloc(sizeof(int) * (size_t)N_NODES * 2);
    int*    rowptr  = (int*)   walloc(sizeof(int) * (N_NODES + 1));
    int*    bsum    = (int*)   walloc(sizeof(int) * 256);
    ush*    xb      = (ush*)   walloc(sizeof(ush) * (size_t)N_NODES * 128);
    ush*    a1      = (ush*)   walloc(sizeof(ush) * (size_t)N_NODES * 128);
    ush*    a2      = (ush*)   walloc(sizeof(ush) * (size_t)N_NODES * 128);
    short*  Wh3     = (short*) walloc(sizeof(short) * (size_t)3 * NB * 128 * 128);

    // Runtime chunk-size selection: T chunk must fit in the remaining ws.
    // 20000 % chunk_n == 0 for all candidates. Prefer a single chunk
    // (3 accumT + 3 gemm2 dispatches total).
    int chunk_n = 2000;
    {
        const int cand[4] = {20000, 10000, 4000, 2000};
        for (int i = 0; i < 4; i++) {
            size_t need = (size_t)cand[i] * TLD * sizeof(ush);
            chunk_n = cand[i];
            if (off + need <= ws_size) break;
        }
    }
    ush* T = (ush*)walloc((size_t)chunk_n * TLD * sizeof(ush));

    int* srcv = e32;
    int* dstv = e32 + E_EDGES;
    int* hist   = histcur;
    int* cursor = histcur + N_NODES;

    detect_kernel<<<1, 1024, 0, stream>>>((const unsigned int*)eix, flag);
    decode_edges<<<(2 * E_EDGES + 255) / 256, 256, 0, stream>>>(eix, flag, e32, 2 * E_EDGES);
    edge_basis<<<(E_EDGES + 255) / 256, 256, 0, stream>>>(ea, Wp1, bp1, Wp2, bp2, fb);

    // CSR binned by dst; hierarchical scan; built once, reused across 3 layers
    const int NBLK = (N_NODES + 255) / 256;    // 79
    zero_int<<<(N_NODES * 2 + 255) / 256, 256, 0, stream>>>(histcur, N_NODES * 2);
    hist_kernel<<<(E_EDGES + 255) / 256, 256, 0, stream>>>(dstv, hist);
    scan_blk<<<NBLK, 256, 0, stream>>>(hist, rowptr, bsum, N_NODES);
    scan_top<<<1, 256, 0, stream>>>(bsum, NBLK);
    scan_add<<<NBLK, 256, 0, stream>>>(rowptr, bsum, N_NODES);
    perm_kernel<<<(E_EDGES + 255) / 256, 256, 0, stream>>>(dstv, rowptr, cursor, eperm);
    pack_rec<<<(E_EDGES + EPAD + 255) / 256, 256, 0, stream>>>(eperm, srcv, fb, rec);

    packW3_kernel<<<(3 * NB * 4 * 8 * 64 + 255) / 256, 256, 0, stream>>>(
        W[0], Wr[0], W[1], Wr[1], W[2], Wr[2], Wh3);
    conv_xb<<<(N_NODES * CIN / 4 + 255) / 256, 256, 0, stream>>>(x, xb);

    const ush* actin = xb;
    for (int l = 0; l < 3; l++) {
        const short* Wh = Wh3 + (size_t)l * NB * 128 * 128;
        ush* actout = (l == 0) ? a1 : (l == 1) ? a2 : nullptr;
        for (int n0 = 0; n0 < N_NODES; n0 += chunk_n) {
            int cn = (n0 + chunk_n <= N_NODES) ? chunk_n : (N_NODES - n0);
            int nmt = cn / 16;
            accumT_kernel<<<cn, 64, 0, stream>>>(actin, rowptr, rec, T, n0);
            gemm2_kernel<<<nmt, 1024, 0, stream>>>(
                T, actin, Wh, b[l], actout, (l == 2) ? out : nullptr,
                n0, (l < 2) ? 1 : 0);
        }
        if (l == 0) actin = a1; else if (l == 1) actin = a2;
    }
}

// Round 15
// 518.716 us; speedup vs baseline: 1.4295x; 1.0156x over previous
//
#include <hip/hip_runtime.h>
#include <hip/hip_bf16.h>
#include <hip/hip_fp16.h>

#define N_NODES 20000
#define E_EDGES 320000
#define CIN 128
#define HDIM 128
#define EDGE_DIM 16
#define SDIM 3
#define KS 3
#define KK 27           // 3^3 kernel weight matrices
#define NB 28           // 27 spline blocks + 1 root-weight block
#define KSTEPS 112      // NB*128/32 k-steps of the fused GEMM
#define TLD (KK * 128)  // node-major T leading dim = 3456 shorts (root not stored)
#define RLD 32          // per-edge record stride (floats): [srcp|pad3|w27|pad] = 128 B
#define EPAD 16         // zero-padded tail records (covers depth-2 batch preload)
#define MLP_HID 6

typedef __attribute__((ext_vector_type(8))) short v8s;   // 8 bf16 (4 VGPRs)
typedef __attribute__((ext_vector_type(4))) float v4f;   // MFMA accumulator
typedef unsigned short ush;

static __device__ __forceinline__ short f2bf(float v) {
    unsigned u = __float_as_uint(v);
    unsigned r = (u + 0x7fffu + ((u >> 16) & 1u)) >> 16;   // RTNE
    return (short)r;
}
static __device__ __forceinline__ float bf2f_lo(unsigned u) {   // low short
    return __uint_as_float(u << 16);
}
static __device__ __forceinline__ float bf2f_hi(unsigned u) {   // high short
    return __uint_as_float(u & 0xffff0000u);
}
static __device__ __forceinline__ unsigned pack2bf(float a, float b) {
    return ((unsigned)(ush)f2bf(a)) | (((unsigned)(ush)f2bf(b)) << 16);
}

// ---------------------------------------------------------------------------
// edge_index dtype detect + decode (int64 vs int32 storage)
// ---------------------------------------------------------------------------
__global__ void detect_kernel(const unsigned int* __restrict__ e, int* __restrict__ flag) {
    __shared__ int s_nz;
    if (threadIdx.x == 0) s_nz = 0;
    __syncthreads();
    unsigned int v = e[threadIdx.x * 2 + 1];
    if (v != 0) atomicAdd(&s_nz, 1);
    __syncthreads();
    if (threadIdx.x == 0) *flag = (s_nz > 0) ? 1 : 0;
}

__global__ void decode_edges(const void* __restrict__ eraw, const int* __restrict__ flag,
                             int* __restrict__ e32, int n) {
    int i = blockIdx.x * blockDim.x + threadIdx.x;
    if (i >= n) return;
    if (*flag) e32[i] = ((const int*)eraw)[i];
    else       e32[i] = (int)(((const long long*)eraw)[i]);
}

// ---------------------------------------------------------------------------
// Edge MLP (16->6 relu ->3 sigmoid) -> (frac[3], lo[3]) per edge, packed 16 B.
// ---------------------------------------------------------------------------
__global__ void edge_basis(const float* __restrict__ ea,
                           const float* __restrict__ Wp1, const float* __restrict__ bp1,
                           const float* __restrict__ Wp2, const float* __restrict__ bp2,
                           float4* __restrict__ fb) {
    __shared__ float sW1[EDGE_DIM * MLP_HID];
    __shared__ float sb1[MLP_HID];
    __shared__ float sW2[MLP_HID * SDIM];
    __shared__ float sb2[SDIM];
    int t = threadIdx.x;
    if (t < EDGE_DIM * MLP_HID) sW1[t] = Wp1[t];
    if (t < MLP_HID)            sb1[t] = bp1[t];
    if (t < MLP_HID * SDIM)     sW2[t] = Wp2[t];
    if (t < SDIM)               sb2[t] = bp2[t];
    __syncthreads();
    int e = blockIdx.x * blockDim.x + t;
    if (e >= E_EDGES) return;

    float a[EDGE_DIM];
#pragma unroll
    for (int i = 0; i < EDGE_DIM; i++) a[i] = ea[(long)e * EDGE_DIM + i];

    float hid[MLP_HID];
#pragma unroll
    for (int j = 0; j < MLP_HID; j++) {
        float s = sb1[j];
#pragma unroll
        for (int i = 0; i < EDGE_DIM; i++) s += a[i] * sW1[i * MLP_HID + j];
        hid[j] = fmaxf(s, 0.f);
    }

    float fr[SDIM];
    unsigned lp = 0;
#pragma unroll
    for (int d = 0; d < SDIM; d++) {
        float s = sb2[d];
#pragma unroll
        for (int j = 0; j < MLP_HID; j++) s += hid[j] * sW2[j * SDIM + d];
        float u = 1.f / (1.f + expf(-s));
        float v = u * (float)(KS - 1);
        float l = floorf(v);
        l = fminf(fmaxf(l, 0.f), (float)(KS - 2));
        fr[d] = v - l;
        lp |= ((unsigned)(int)l) << (8 * d);
    }
    float4 o;
    o.x = fr[0]; o.y = fr[1]; o.z = fr[2]; o.w = __uint_as_float(lp);
    fb[e] = o;
}

// ---------------------------------------------------------------------------
// CSR build binned by dst — built once, reused for 3 layers.
// Hierarchical 3-dispatch scan.
// ---------------------------------------------------------------------------
__global__ void zero_int(int* __restrict__ p, int n) {
    int i = blockIdx.x * blockDim.x + threadIdx.x;
    if (i < n) p[i] = 0;
}

__global__ void hist_kernel(const int* __restrict__ dst, int* __restrict__ hist) {
    int e = blockIdx.x * blockDim.x + threadIdx.x;
    if (e >= E_EDGES) return;
    atomicAdd(&hist[dst[e]], 1);
}

__global__ void scan_blk(const int* __restrict__ hist, int* __restrict__ rowptr,
                         int* __restrict__ bsum, int B) {
    __shared__ int sh[256];
    int i = blockIdx.x * 256 + threadIdx.x;
    int v = (i < B) ? hist[i] : 0;
    sh[threadIdx.x] = v;
    __syncthreads();
    for (int off = 1; off < 256; off <<= 1) {
        int t = (threadIdx.x >= off) ? sh[threadIdx.x - off] : 0;
        __syncthreads();
        sh[threadIdx.x] += t;
        __syncthreads();
    }
    if (i < B) rowptr[i] = sh[threadIdx.x] - v;        // block-local exclusive
    if (threadIdx.x == 255) bsum[blockIdx.x] = sh[255];
}

__global__ void scan_top(int* __restrict__ bsum, int nb) {
    __shared__ int sh[256];
    int v = (threadIdx.x < nb) ? bsum[threadIdx.x] : 0;
    sh[threadIdx.x] = v;
    __syncthreads();
    for (int off = 1; off < 256; off <<= 1) {
        int t = (threadIdx.x >= off) ? sh[threadIdx.x - off] : 0;
        __syncthreads();
        sh[threadIdx.x] += t;
        __syncthreads();
    }
    if (threadIdx.x < nb) bsum[threadIdx.x] = sh[threadIdx.x] - v;   // exclusive
}

__global__ void scan_add(int* __restrict__ rowptr, const int* __restrict__ bsum, int B) {
    int i = blockIdx.x * 256 + threadIdx.x;
    if (i < B) rowptr[i] += bsum[blockIdx.x];
    if (i == 0) rowptr[B] = E_EDGES;
}

__global__ void perm_kernel(const int* __restrict__ dst,
                            const int* __restrict__ rowptr, int* __restrict__ cursor,
                            int* __restrict__ eperm) {
    int e = blockIdx.x * blockDim.x + threadIdx.x;
    if (e >= E_EDGES) return;
    int bin = dst[e];
    int pos = rowptr[bin] + atomicAdd(&cursor[bin], 1);
    eperm[pos] = e;
}

// ---------------------------------------------------------------------------
// Pack per-edge metadata into CSR order as 128-B records:
// float[32] = [ srcp(bits) | pad x3 | w27[0..26] | pad ].
// Records >= E_EDGES are zeroed (srcp=0, w=0).
// ---------------------------------------------------------------------------
__global__ void pack_rec(const int* __restrict__ eperm, const int* __restrict__ src,
                         const float4* __restrict__ fb, float* __restrict__ rec) {
    int j = blockIdx.x * blockDim.x + threadIdx.x;
    if (j >= E_EDGES + EPAD) return;
    float out[RLD];
#pragma unroll
    for (int q = 0; q < RLD; q++) out[q] = 0.f;
    if (j < E_EDGES) {
        int e = eperm[j];
        out[0] = __int_as_float(src[e]);
        float4 f = fb[e];
        unsigned lp = __float_as_uint(f.w);
        float fr[3] = {f.x, f.y, f.z};
        float t[3][3];
#pragma unroll
        for (int d = 0; d < 3; d++) {
            int lo = (lp >> (8 * d)) & 255;
            float fd = fr[d];
#pragma unroll
            for (int q = 0; q < 3; q++)
                t[d][q] = (q == lo) ? (1.f - fd) : (q == lo + 1) ? fd : 0.f;
        }
#pragma unroll
        for (int k2 = 0; k2 < 3; k2++)
#pragma unroll
            for (int k1 = 0; k1 < 3; k1++)
#pragma unroll
                for (int k0 = 0; k0 < 3; k0++)
                    out[4 + k2 * 9 + k1 * 3 + k0] = t[0][k0] * t[1][k1] * t[2][k2];
    }
    float* op = rec + (size_t)j * RLD;
#pragma unroll
    for (int q = 0; q < RLD / 4; q++) *(float4*)(op + 4 * q) = *(float4*)(out + 4 * q);
}

// ---------------------------------------------------------------------------
// Pack [W (27 blocks) | Wr] of ALL 3 LAYERS -> bf16 MFMA B-fragment layout.
// Layout [layer][flat_ks=kb*4+ks][nt][64][8] — one fused K=3584 B panel.
// ---------------------------------------------------------------------------
__global__ void packW3_kernel(const float* __restrict__ W0, const float* __restrict__ Wr0,
                              const float* __restrict__ W1, const float* __restrict__ Wr1,
                              const float* __restrict__ W2, const float* __restrict__ Wr2,
                              short* __restrict__ hi) {
    int gid = blockIdx.x * blockDim.x + threadIdx.x;
    if (gid >= 3 * NB * 4 * 8 * 64) return;
    int lane = gid & 63;
    int nt = (gid >> 6) & 7;
    int ks = (gid >> 9) & 3;
    int kb2 = gid >> 11;           // 0..83
    int layer = kb2 / NB;
    int kb = kb2 - layer * NB;
    const float* W  = (layer == 0) ? W0  : (layer == 1) ? W1  : W2;
    const float* Wr = (layer == 0) ? Wr0 : (layer == 1) ? Wr1 : Wr2;
    int i0 = ks * 32 + ((lane >> 4) & 3) * 8;
    int o = nt * 16 + (lane & 15);
    const float* src = (kb < KK) ? (W + (long)kb * 16384 + (long)i0 * 128 + o)
                                 : (Wr + (long)i0 * 128 + o);
    long off = ((long)(((size_t)layer * NB + kb) * 4 + ks) * 8 + nt) * 64 * 8
             + (long)lane * 8;
#pragma unroll
    for (int j = 0; j < 8; j++) {
        float v = src[(long)j * 128];
        hi[off + j] = f2bf(v);
    }
}

// ---------------------------------------------------------------------------
// x (fp32) -> xb (bf16 row-major) once; later layers' activations are written
// bf16 row-major by the GEMM epilogue directly.
// ---------------------------------------------------------------------------
__global__ void conv_xb(const float* __restrict__ x, ush* __restrict__ xb) {
    int i = blockIdx.x * blockDim.x + threadIdx.x;
    if (i >= N_NODES * CIN / 4) return;
    float4 v = ((const float4*)x)[i];
    uint2 d;
    d.x = pack2bf(v.x, v.y);
    d.y = pack2bf(v.z, v.w);
    ((uint2*)xb)[i] = d;
}

// ---------------------------------------------------------------------------
// accumT v10: 4 WAVES PER 256-THREAD BLOCK, ONE NODE PER WAVE, each wave
// with a PRIVATE 2x1KB LDS slot pair (8 KB/block). The R11 scalarization
// trap doesn't apply here: v9 moved all per-edge metadata onto VECTOR paths
// (global loads + ds_read, both counted-wait), so a wave-varying node index
// costs nothing — and 256-thread workgroups lift the residency cap from
// ~16 waves/CU (64-thr dispatch granularity) to the 32-wave hardware cap.
// Per-wave pipeline identical to v9: 8-edge record batches staged
// global->VGPR->LDS double-buffer; weights re-read via in-order ds_read;
// act rows issued batch-front at depth 8. No SMEM in the hot loop.
// No __syncthreads needed: slots are wave-private, DS is in-order per wave.
// ---------------------------------------------------------------------------
__global__ __launch_bounds__(256) void accumT_kernel(
    const ush* __restrict__ act, const int* __restrict__ rowptr,
    const float* __restrict__ rec, ush* __restrict__ T, int n0, int nmax)
{
    __shared__ float lb[4][2][256];        // per-wave private slot pairs
    int lane = threadIdx.x & 63;
    int wave = threadIdx.x >> 6;
    int n = n0 + blockIdx.x * 4 + wave;
    if (n >= nmax) return;
    int jb = rowptr[n], je = rowptr[n + 1];
    int d = je - jb;

    float acc[KK][2];
#pragma unroll
    for (int k = 0; k < KK; k++) { acc[k][0] = 0.f; acc[k][1] = 0.f; }

    const ush* actl = act + lane * 2;                 // channel-pair base

    if (d > 0) {
        int nb = (d + 7) >> 3;                        // 8-edge batches
        const float4* rb = (const float4*)rec + (size_t)jb * 8;

        // prologue: stage batch 0, preload batch 1
        float4 g = rb[lane];
        *(float4*)(&lb[wave][0][lane * 4]) = g;       // ds_write_b128
        if (nb > 1) g = rb[(size_t)64 + lane];

        for (int b = 0; b < nb; ++b) {
            int slot = b & 1;
            // stage batch b+1 into the other slot (its old content, batch
            // b-1, was consumed last iteration; DS is in-order per wave).
            if (b + 1 < nb) *(float4*)(&lb[wave][slot ^ 1][lane * 4]) = g;
            if (b + 2 < nb) g = rb[(size_t)(b + 2) * 64 + lane];

            // batch-front: read 8 srcp (LDS broadcast), issue 8 act loads
            int sidx[8];
#pragma unroll
            for (int e = 0; e < 8; e++)
                sidx[e] = __float_as_int(lb[wave][slot][e * 32]);
            unsigned xa[8];
#pragma unroll
            for (int e = 0; e < 8; e++)
                xa[e] = *(const unsigned*)(actl + (size_t)sidx[e] * 128);

            int rem = d - (b << 3);                   // valid edges this batch
#pragma unroll
            for (int e = 0; e < 8; e++) {
                if (e < rem) {                        // wave-uniform guard
                    float w[28];
#pragma unroll
                    for (int q = 0; q < 7; q++)
                        *(float4*)(w + 4 * q) =
                            *(const float4*)(&lb[wave][slot][e * 32 + 4 + 4 * q]);
                    float x0 = bf2f_lo(xa[e]), x1 = bf2f_hi(xa[e]);
#pragma unroll
                    for (int k = 0; k < KK; k++) {
                        acc[k][0] += w[k] * x0;
                        acc[k][1] += w[k] * x1;
                    }
                }
            }
        }
    }

    ush* tp = T + (size_t)(n - n0) * TLD + lane * 2;
#pragma unroll
    for (int k = 0; k < KK; k++) {
        *(unsigned*)(tp + (size_t)k * 128) = pack2bf(acc[k][0], acc[k][1]);
    }
}

// ---------------------------------------------------------------------------
// gemm2 v9: out[n,o] = [T_row(3456) | act_row(128)] . Wall(3584x128) + bias
// 1024 threads / 16 waves, TWO m-tiles per block. R13 diagnosis: gemm2 is
// L2-BW-bound on B-panel re-reads (1250 blocks x 917 KB = 1.15 GB/layer
// ~ 50% of L2 ceiling). Pairing m-tiles halves that (each B fragment feeds
// 2 MFMAs) at the R10-proven 625-block granularity (2 blocks/CU resident).
// Wave owns 7 k-steps, fully unrolled. 16-way cross-wave reduce via LDS
// (69.6 KB) in 4 passes (2 m-tiles x 2 column halves).
// ---------------------------------------------------------------------------
__global__ __launch_bounds__(1024) void gemm2_kernel(
    const ush* __restrict__ T, const ush* __restrict__ act,
    const short* __restrict__ Wh, const float* __restrict__ bias,
    ush* __restrict__ actout, float* __restrict__ fout,
    int n0, int nmt, int relu)
{
    __shared__ float S[1024][17];
    int lane = threadIdx.x & 63;
    int wave = threadIdx.x >> 6;               // k-slice 0..15
    int mtr0 = blockIdx.x * 2;
    int mv = (nmt - mtr0 >= 2) ? 2 : 1;

    v4f acc[2][8];
#pragma unroll
    for (int m = 0; m < 2; m++)
#pragma unroll
        for (int nt = 0; nt < 8; nt++) acc[m][nt] = (v4f){0.f, 0.f, 0.f, 0.f};

    int r15 = lane & 15;
    int sub = (lane >> 4) & 3;
    int arow0 = mtr0 * 16 + r15;
    int arow1 = arow0 + ((mv > 1) ? 16 : 0);   // clamped duplicate on tail
    const ush* tp0 = T + (size_t)arow0 * TLD + sub * 8;
    const ush* tp1 = T + (size_t)arow1 * TLD + sub * 8;
    const ush* ap0 = act + (size_t)(n0 + arow0) * 128 + sub * 8;
    const ush* ap1 = act + (size_t)(n0 + arow1) * 128 + sub * 8;

    int ks0 = wave * (KSTEPS / 16);            // 7 k-steps per wave
#pragma unroll
    for (int i = 0; i < KSTEPS / 16; i++) {
        int ks = ks0 + i;
        v8s a0 = (ks < KK * 4) ? *(const v8s*)(tp0 + ks * 32)
                               : *(const v8s*)(ap0 + (ks - KK * 4) * 32);
        v8s a1 = (ks < KK * 4) ? *(const v8s*)(tp1 + ks * 32)
                               : *(const v8s*)(ap1 + (ks - KK * 4) * 32);
        const short* wb = Wh + (size_t)ks * 4096 + (size_t)lane * 8;
#pragma unroll
        for (int nt = 0; nt < 8; nt++) {
            v8s b = *(const v8s*)(wb + (size_t)nt * 512);
            acc[0][nt] = __builtin_amdgcn_mfma_f32_16x16x32_bf16(a0, b, acc[0][nt], 0, 0, 0);
            acc[1][nt] = __builtin_amdgcn_mfma_f32_16x16x32_bf16(a1, b, acc[1][nt], 0, 0, 0);
        }
    }

    // 16-way cross-wave reduce + epilogue: 4 passes (2 m-tiles x 2 halves)
    int r  = threadIdx.x >> 6;                 // output row in m-tile (0..15)
    int cl = threadIdx.x & 63;                 // column within the 64-col half
#pragma unroll
    for (int m = 0; m < 2; m++) {
        int row = n0 + (mtr0 + m) * 16 + r;
#pragma unroll
        for (int p = 0; p < 2; p++) {
            __syncthreads();
#pragma unroll
            for (int q = 0; q < 16; q++)
                S[threadIdx.x][q] = acc[m][p * 4 + (q >> 2)][q & 3];
            __syncthreads();
            if (m < mv) {
                int c = p * 64 + cl;                   // global output column
                int ln  = (cl & 15) + 16 * (r >> 2);   // source lane of C-frag
                int idx = (cl >> 4) * 4 + (r & 3);     // nt_local*4 + reg
                float s = 0.f;
#pragma unroll
                for (int w = 0; w < 16; w++) s += S[w * 64 + ln][idx];
                s += bias[c];
                if (relu) s = fmaxf(s, 0.f);
                if (actout) {
                    actout[(size_t)row * 128 + c] = (ush)f2bf(s);
                } else {
                    fout[(size_t)row * 128 + c] = s;
                }
            }
        }
    }
}

// ---------------------------------------------------------------------------
extern "C" void kernel_launch(void* const* d_in, const int* in_sizes, int n_in,
                              void* d_out, int out_size, void* d_ws, size_t ws_size,
                              hipStream_t stream) {
    const float* x   = (const float*)d_in[0];
    const void*  eix = d_in[1];
    const float* ea  = (const float*)d_in[2];
    const float* Wp1 = (const float*)d_in[3];
    const float* bp1 = (const float*)d_in[4];
    const float* Wp2 = (const float*)d_in[5];
    const float* bp2 = (const float*)d_in[6];
    const float* W[3]  = {(const float*)d_in[7],  (const float*)d_in[10], (const float*)d_in[13]};
    const float* Wr[3] = {(const float*)d_in[8],  (const float*)d_in[11], (const float*)d_in[14]};
    const float* b[3]  = {(const float*)d_in[9],  (const float*)d_in[12], (const float*)d_in[15]};
    float* out = (float*)d_out;

    char* ws = (char*)d_ws;
    size_t off = 0;
    auto walloc = [&](size_t bytes) -> void* {
        void* p = ws + off;
        off = (off + bytes + 255) & ~(size_t)255;
        return p;
    };
    int*    flag    = (int*)   walloc(sizeof(int));
    int*    e32     = (int*)   walloc(sizeof(int) * 2 * E_EDGES);
    float4* fb      = (float4*)walloc(sizeof(float4) * (size_t)E_EDGES);
    int*    eperm   = (int*)   walloc(sizeof(int) * E_EDGES);
    float*  rec     = (float*) walloc(sizeof(float) * (size_t)(E_EDGES + EPAD) * RLD);
    int*    histcur = (int*)   walloc(sizeof(int) * (size_t)N_NODES * 2);
    int*    rowptr  = (int*)   walloc(sizeof(int) * (N_NODES + 1));
    int*    bsum    = (int*)   walloc(sizeof(int) * 256);
    ush*    xb      = (ush*)   walloc(sizeof(ush) * (size_t)N_NODES * 128);
    ush*    a1      = (ush*)   walloc(sizeof(ush) * (size_t)N_NODES * 128);
    ush*    a2      = (ush*)   walloc(sizeof(ush) * (size_t)N_NODES * 128);
    short*  Wh3     = (short*) walloc(sizeof(short) * (size_t)3 * NB * 128 * 128);

    // Runtime chunk-size selection: T chunk must fit in the remaining ws.
    // 20000 % chunk_n == 0 for all candidates. Prefer a single chunk.
    int chunk_n = 2000;
    {
        const int cand[4] = {20000, 10000, 4000, 2000};
        for (int i = 0; i < 4; i++) {
            size_t need = (size_t)cand[i] * TLD * sizeof(ush);
            chunk_n = cand[i];
            if (off + need <= ws_size) break;
        }
    }
    ush* T = (ush*)walloc((size_t)chunk_n * TLD * sizeof(ush));

    int* srcv = e32;
    int* dstv = e32 + E_EDGES;
    int* hist   = histcur;
    int* cursor = histcur + N_NODES;

    detect_kernel<<<1, 1024, 0, stream>>>((const unsigned int*)eix, flag);
    decode_edges<<<(2 * E_EDGES + 255) / 256, 256, 0, stream>>>(eix, flag, e32, 2 * E_EDGES);
    edge_basis<<<(E_EDGES + 255) / 256, 256, 0, stream>>>(ea, Wp1, bp1, Wp2, bp2, fb);

    // CSR binned by dst; hierarchical scan; built once, reused across 3 layers
    const int NBLK = (N_NODES + 255) / 256;    // 79
    zero_int<<<(N_NODES * 2 + 255) / 256, 256, 0, stream>>>(histcur, N_NODES * 2);
    hist_kernel<<<(E_EDGES + 255) / 256, 256, 0, stream>>>(dstv, hist);
    scan_blk<<<NBLK, 256, 0, stream>>>(hist, rowptr, bsum, N_NODES);
    scan_top<<<1, 256, 0, stream>>>(bsum, NBLK);
    scan_add<<<NBLK, 256, 0, stream>>>(rowptr, bsum, N_NODES);
    perm_kernel<<<(E_EDGES + 255) / 256, 256, 0, stream>>>(dstv, rowptr, cursor, eperm);
    pack_rec<<<(E_EDGES + EPAD + 255) / 256, 256, 0, stream>>>(eperm, srcv, fb, rec);

    packW3_kernel<<<(3 * NB * 4 * 8 * 64 + 255) / 256, 256, 0, stream>>>(
        W[0], Wr[0], W[1], Wr[1], W[2], Wr[2], Wh3);
    conv_xb<<<(N_NODES * CIN / 4 + 255) / 256, 256, 0, stream>>>(x, xb);

    const ush* actin = xb;
    for (int l = 0; l < 3; l++) {
        const short* Wh = Wh3 + (size_t)l * NB * 128 * 128;
        ush* actout = (l == 0) ? a1 : (l == 1) ? a2 : nullptr;
        for (int n0 = 0; n0 < N_NODES; n0 += chunk_n) {
            int cn = (n0 + chunk_n <= N_NODES) ? chunk_n : (N_NODES - n0);
            int nmt = cn / 16;
            accumT_kernel<<<(cn + 3) / 4, 256, 0, stream>>>(
                actin, rowptr, rec, T, n0, n0 + cn);
            gemm2_kernel<<<(nmt + 1) / 2, 1024, 0, stream>>>(
                T, actin, Wh, b[l], actout, (l == 2) ? out : nullptr,
                n0, nmt, (l < 2) ? 1 : 0);
        }
        if (l == 0) actin = a1; else if (l == 1) actin = a2;
    }
}